// Round 10
// baseline (445.935 us; speedup 1.0000x reference)
//
#include <hip/hip_runtime.h>

typedef unsigned short u16;
typedef unsigned int u32;
typedef __bf16 bf16x8 __attribute__((ext_vector_type(8)));
typedef float f32x4 __attribute__((ext_vector_type(4)));

#define NPAPER 100000
#define NAUTH  50000
#define NROWS_ALL (2 * NPAPER + NAUTH)

struct alignas(16) U4 { u32 a, b, c, d; };
struct alignas(8)  U2 { u32 a, b; };
struct alignas(16) F4 { float x, y, z, w; };

__device__ __forceinline__ float bf2f(u16 u) {
    union { u32 i; float f; } v; v.i = ((u32)u) << 16; return v.f;
}
__device__ __forceinline__ u16 f2bf(float f) {
    union { float f; u32 i; } v; v.f = f;
    u32 u = v.i;
    return (u16)((u + 0x7FFFu + ((u >> 16) & 1u)) >> 16);
}

// flags: [0]=idx_is_int64 [1]=x_is_f32 [2]=W_is_f32 [3]=b_is_f32
__device__ __forceinline__ float ldf(const void* p, size_t i, int f32) {
    return f32 ? ((const float*)p)[i] : bf2f(((const u16*)p)[i]);
}

__global__ void detect_dtypes(const int* __restrict__ e, const u32* __restrict__ x,
                              const u32* __restrict__ w, const u32* __restrict__ bb,
                              int* __restrict__ flags)
{
    int t = threadIdx.x, wave = t >> 6, lane = t & 63;
    if (wave == 0) {
        int v = e[lane];
        unsigned long long m = __ballot((lane & 1) && v == 0);
        if (lane == 0) flags[0] = (__popcll(m) >= 24) ? 1 : 0;
    } else {
        const u32* p = (wave == 1) ? x : ((wave == 2) ? w : bb);
        u32 wd = p[lane];
        int ex = (int)((wd >> 7) & 0xFFu);   // exponent of low-half-as-bf16
        unsigned long long m = __ballot(ex >= 105 && ex <= 140);
        if (lane == 0) flags[wave] = (__popcll(m) >= 40) ? 0 : 1;   // 1 = f32
    }
}

// ---- epilogue column permutation for GEMM B-rows ----
// B-row j (0..127) holds PHYSICAL output column n(j):
//   s=j>>6, u=j&63, c=u>>4, fr=u&15  ->  n = s*64 + fr*4 + c
__device__ __forceinline__ int permcol(int j) {
    int s = j >> 6, u = j & 63, c = u >> 4, fr = u & 15;
    return s * 64 + fr * 4 + c;
}

// ---- fused prologue: convert_x (dual layout) + prep_weights + hist3 ----
__global__ __launch_bounds__(256) void fused_pre(
    const void* __restrict__ xp, const void* __restrict__ xa,
    u16* __restrict__ xpb, u16* __restrict__ xab,
    u16* __restrict__ xpbT, u16* __restrict__ xabT,
    const void* __restrict__ Wm1, const void* __restrict__ b1, const void* __restrict__ Wr1,
    const void* __restrict__ Wm2, const void* __restrict__ b2, const void* __restrict__ Wr2,
    u16* __restrict__ WTp1, u16* __restrict__ WTa1,
    float* __restrict__ biasp1, float* __restrict__ biasa1,
    u16* __restrict__ WTp2, u16* __restrict__ WTa2,
    float* __restrict__ biasp2, float* __restrict__ biasa2,
    const int* __restrict__ e0d, const int* __restrict__ e1d, const int* __restrict__ e2d,
    int E0, int E1, int E2, int nb0, int nb1,
    int* __restrict__ cnt, int nbc,
    const int* __restrict__ flags)
{
    int b = blockIdx.x;
    int t = threadIdx.x;
    if (b < nbc) {
        // ---- convert_x: row-major copy (for agg gathers) + tiled copy (GEMM root) ----
        int f32 = flags[1];
        size_t i = ((size_t)b * 256 + t) * 8;
        const size_t np = (size_t)NPAPER * 128, ntot = np + (size_t)NAUTH * 128;
        if (i >= ntot) return;
        const void* s; u16* d; u16* dT; size_t off;
        if (i < np) { s = xp; d = xpb; dT = xpbT; off = i; }
        else        { s = xa; d = xab; dT = xabT; off = i - np; }
        alignas(16) u16 o[8];
        if (f32) {
            const F4* f = (const F4*)((const float*)s + off);
            F4 f0 = f[0], f1 = f[1];
            o[0] = f2bf(f0.x); o[1] = f2bf(f0.y); o[2] = f2bf(f0.z); o[3] = f2bf(f0.w);
            o[4] = f2bf(f1.x); o[5] = f2bf(f1.y); o[6] = f2bf(f1.z); o[7] = f2bf(f1.w);
        } else {
            *(U4*)o = *(const U4*)((const u16*)s + off);
        }
        *(U4*)(d + off) = *(const U4*)o;
        {   // tiled: addr(r,k) = (r>>4)*2048 + (k>>3)*128 + (r&15)*8
            size_t row = off >> 7;
            int k = (int)(off & 127);
            *(U4*)(dT + (row >> 4) * 2048 + (size_t)(k >> 3) * 128 + (row & 15) * 8)
                = *(const U4*)o;
        }
        return;
    }
    b -= nbc;
    if (b < 642) {
        // ---- prep_weights (both layers) ----
        int half = b >= 321;
        const void* Wm = half ? Wm2 : Wm1;
        const void* bb = half ? b2  : b1;
        const void* Wr = half ? Wr2 : Wr1;
        u16* WTp = half ? WTp2 : WTp1;
        u16* WTa = half ? WTa2 : WTa1;
        float* biasp = half ? biasp2 : biasp1;
        float* biasa = half ? biasa2 : biasa1;

        int wf = flags[2], bf = flags[3];
        int tid = (b - half * 321) * 256 + t;
        if (tid < 49152) {
            int j = tid / 384, k = tid - j * 384;
            int n = permcol(j);
            float v;
            if (k < 128)      v = ldf(Wm, k * 128 + n, wf);
            else if (k < 256) v = ldf(Wm, 16384 + (k - 128) * 128 + n, wf);
            else              v = ldf(Wr, (k - 256) * 128 + n, wf)
                                + ldf(Wr, 16384 + (k - 256) * 128 + n, wf);
            WTp[j * 384 + k] = f2bf(v);
        } else if (tid < 81920) {
            int idx = tid - 49152;
            int j = idx >> 8, k = idx & 255;
            int n = permcol(j);
            float v = (k < 128) ? ldf(Wm, 2 * 16384 + k * 128 + n, wf)
                                : ldf(Wr, 2 * 16384 + (k - 128) * 128 + n, wf);
            WTa[j * 256 + k] = f2bf(v);
        } else if (tid < 82176) {
            int i = tid - 81920;
            if (i < 128) biasp[i] = ldf(bb, i, bf) + ldf(bb, 128 + i, bf);
            else         biasa[i - 128] = ldf(bb, 256 + (i - 128), bf);
        }
        return;
    }
    b -= 642;
    {
        // ---- hist3 ----
        const int* dptr; int E, base, i;
        if (b < nb0)            { dptr = e0d; E = E0; base = 0;          i = b * 256 + t; }
        else if (b < nb0 + nb1) { dptr = e1d; E = E1; base = NPAPER;     i = (b - nb0) * 256 + t; }
        else                    { dptr = e2d; E = E2; base = 2 * NPAPER; i = (b - nb0 - nb1) * 256 + t; }
        if (i >= E) return;
        int d = dptr[flags[0] ? 2 * i : i];
        atomicAdd(&cnt[base + d], 1);
    }
}

__global__ __launch_bounds__(256) void scan_blksum(
    const int* __restrict__ cnt, int N, int* __restrict__ partials)
{
    __shared__ int ws[4];
    int t = threadIdx.x, lane = t & 63, wave = t >> 6;
    int i0 = blockIdx.x * 1024 + t * 4;
    int s = 0;
    #pragma unroll
    for (int j = 0; j < 4; ++j) {
        int i = i0 + j;
        if (i < N) s += cnt[i];
    }
    #pragma unroll
    for (int off = 32; off; off >>= 1) s += __shfl_xor(s, off);
    if (lane == 0) ws[wave] = s;
    __syncthreads();
    if (t == 0) partials[blockIdx.x] = ws[0] + ws[1] + ws[2] + ws[3];
}

__global__ __launch_bounds__(256) void scan_partials(int* __restrict__ partials, int nb)
{
    __shared__ int bs[256];
    int t = threadIdx.x;
    bs[t] = (t < nb) ? partials[t] : 0;
    __syncthreads();
    for (int off = 1; off < 256; off <<= 1) {
        int u = (t >= off) ? bs[t - off] : 0;
        __syncthreads();
        bs[t] += u;
        __syncthreads();
    }
    if (t < nb) partials[t] = (t == 0) ? 0 : bs[t - 1];
}

__global__ __launch_bounds__(256) void scan_write(
    const int* __restrict__ cnt, int N, const int* __restrict__ partials,
    int* __restrict__ rowptr, int* __restrict__ cursor)
{
    __shared__ int ws[4];
    int t = threadIdx.x, lane = t & 63, wave = t >> 6;
    int i0 = blockIdx.x * 1024 + t * 4;
    int v[4];
    #pragma unroll
    for (int j = 0; j < 4; ++j) {
        int i = i0 + j;
        v[j] = (i < N) ? cnt[i] : 0;
    }
    int s = v[0] + v[1] + v[2] + v[3];
    int sc = s;
    #pragma unroll
    for (int off = 1; off < 64; off <<= 1) {
        int u = __shfl_up(sc, off);
        if (lane >= off) sc += u;
    }
    if (lane == 63) ws[wave] = sc;
    __syncthreads();
    int woff = 0;
    #pragma unroll
    for (int wv = 0; wv < 3; ++wv) if (wv < wave) woff += ws[wv];
    int run = partials[blockIdx.x] + woff + (sc - s);
    #pragma unroll
    for (int j = 0; j < 4; ++j) {
        int i = i0 + j;
        if (i < N) {
            rowptr[i] = run; cursor[i] = run;
            run += v[j];
            if (i == N - 1) rowptr[N] = run;
        }
    }
}

__global__ __launch_bounds__(256) void scatter3(
    const int* __restrict__ e0s, const int* __restrict__ e0d,
    const int* __restrict__ e1s, const int* __restrict__ e1d,
    const int* __restrict__ e2s, const int* __restrict__ e2d,
    int E0, int E1, int E2, int nb0, int nb1,
    int* __restrict__ cursor, int* __restrict__ srt,
    const int* __restrict__ flags)
{
    int b = blockIdx.x;
    const int* sptr; const int* dptr; int E, base, i;
    if (b < nb0)            { sptr = e0s; dptr = e0d; E = E0; base = 0;          i = b * 256 + threadIdx.x; }
    else if (b < nb0 + nb1) { sptr = e1s; dptr = e1d; E = E1; base = NPAPER;     i = (b - nb0) * 256 + threadIdx.x; }
    else                    { sptr = e2s; dptr = e2d; E = E2; base = 2 * NPAPER; i = (b - nb0 - nb1) * 256 + threadIdx.x; }
    if (i >= E) return;
    int ii = flags[0] ? 2 * i : i;
    int d = dptr[ii];
    int pos = atomicAdd(&cursor[base + d], 1);
    srt[pos] = sptr[ii];
}

// ---- unified CSR gather-mean: TWO adjacent rows per wave ----
// Means are stored in MFMA fragment-tile layout so the GEMM's A-loads are
// line-contiguous:  addr(r,k) = (r>>4)*16*KM + (k>>3)*128 + (r&15)*8 + (k&7)
// Mp: KM=256 (cites cols 0..127, writes cols 128..255); Ma: KM=128.
// Lane l holds cols 2l,2l+1 -> chunk l>>2, elem 2*(l&3).
__device__ __forceinline__ void agg_resolve(int r, const u16* xp, const u16* xa,
                                            u16* Mp, u16* Ma,
                                            const u16*& x, u16*& d)
{
    if (r < NPAPER)          { x = xp; d = Mp + (size_t)(r >> 4) * 4096 + (r & 15) * 8; }
    else if (r < 2 * NPAPER) { int rr = r - NPAPER; x = xa;
                               d = Mp + (size_t)(rr >> 4) * 4096 + (rr & 15) * 8 + 2048; }
    else                     { int rr = r - 2 * NPAPER; x = xp;
                               d = Ma + (size_t)(rr >> 4) * 2048 + (rr & 15) * 8; }
}

__global__ __launch_bounds__(256) void agg_all(
    const u16* __restrict__ xp, const u16* __restrict__ xa,
    const int* __restrict__ rp_all, const int* __restrict__ srt,
    u16* __restrict__ Mp, u16* __restrict__ Ma)
{
    int wid = (blockIdx.x * 256 + threadIdx.x) >> 6;
    int lane = threadIdx.x & 63;
    int r0 = wid * 2;
    if (r0 >= NROWS_ALL) return;
    int has1 = (r0 + 1 < NROWS_ALL);

    int eA0 = rp_all[r0], eA1 = rp_all[r0 + 1];
    int eB0 = eA1, eB1 = has1 ? rp_all[r0 + 2] : eA1;

    const u16 *xA, *xB; u16 *dA, *dB;
    agg_resolve(r0, xp, xa, Mp, Ma, xA, dA);
    agg_resolve(has1 ? r0 + 1 : r0, xp, xa, Mp, Ma, xB, dB);

    float a0A = 0.0f, a1A = 0.0f, a0B = 0.0f, a1B = 0.0f;
    int itA = (eA1 - eA0 + 3) >> 2;
    int itB = (eB1 - eB0 + 3) >> 2;
    int iters = itA > itB ? itA : itB;

#define GATH4(e_, elast_, x_, q0_, q1_) do {                                \
    int el_ = (elast_) - 1;                                                 \
    int i1_ = (e_) + 1, i2_ = (e_) + 2, i3_ = (e_) + 3;                     \
    int c1_ = i1_ < (elast_) ? i1_ : el_;                                   \
    int c2_ = i2_ < (elast_) ? i2_ : el_;                                   \
    int c3_ = i3_ < (elast_) ? i3_ : el_;                                   \
    int s0_ = srt[e_], s1_ = srt[c1_], s2_ = srt[c2_], s3_ = srt[c3_];      \
    u32 p0_ = ((const u32*)((x_) + (size_t)s0_ * 128))[lane];               \
    u32 p1_ = ((const u32*)((x_) + (size_t)s1_ * 128))[lane];               \
    u32 p2_ = ((const u32*)((x_) + (size_t)s2_ * 128))[lane];               \
    u32 p3_ = ((const u32*)((x_) + (size_t)s3_ * 128))[lane];               \
    p1_ = (i1_ < (elast_)) ? p1_ : 0u;                                      \
    p2_ = (i2_ < (elast_)) ? p2_ : 0u;                                      \
    p3_ = (i3_ < (elast_)) ? p3_ : 0u;                                      \
    q0_ += bf2f((u16)(p0_ & 0xFFFFu)) + bf2f((u16)(p1_ & 0xFFFFu))          \
         + bf2f((u16)(p2_ & 0xFFFFu)) + bf2f((u16)(p3_ & 0xFFFFu));         \
    q1_ += bf2f((u16)(p0_ >> 16)) + bf2f((u16)(p1_ >> 16))                  \
         + bf2f((u16)(p2_ >> 16)) + bf2f((u16)(p3_ >> 16));                 \
} while (0)

    for (int k = 0; k < iters; ++k) {
        if (k < itA) GATH4(eA0 + 4 * k, eA1, xA, a0A, a1A);
        if (k < itB) GATH4(eB0 + 4 * k, eB1, xB, a0B, a1B);
    }
#undef GATH4

    int loff = (lane >> 2) * 128 + 2 * (lane & 3);   // tiled lane slot
    float rcpA = 1.0f / fmaxf((float)(eA1 - eA0), 1.0f);
    *(u32*)(dA + loff) = (u32)f2bf(a0A * rcpA) | ((u32)f2bf(a1A * rcpA) << 16);
    if (has1) {
        float rcpB = 1.0f / fmaxf((float)(eB1 - eB0), 1.0f);
        *(u32*)(dB + loff) = (u32)f2bf(a0B * rcpB) | ((u32)f2bf(a1B * rcpB) << 16);
    }
}

// ---- fused GEMM/bias/relu body: out[nrows][128] = [M | root] @ WT^T + bias ----
// 256 rows per block, 8 waves (4x2 grid), 64x64 per wave.  B (WT) staged fully
// into LDS in 2 K-halves (3 barriers/block); A fragments loaded per-lane from
// global, double-buffered -> barrier-free K-loop.  BOTH mean (k<KM) and root
// (k>=KM, rootT) are in fragment-tile layout -> every LOADA reads one
// contiguous 1KB burst.  Epilogue: permuted columns -> vector stores; when
// outT != null also writes a tiled bf16 copy (next layer's root operand).
template<int K, int KM>
__device__ __forceinline__ void gemm_body(
    u16* __restrict__ Bsm, int bx,
    const u16* __restrict__ M, const u16* __restrict__ rootT,
    const u16* __restrict__ WT, const float* __restrict__ bias,
    void* __restrict__ out, u16* __restrict__ outT,
    int out_f32, int nrows, int relu)
{
    constexpr int KSTEPS = K / 32;
    constexpr int KSH    = KSTEPS / 2;
    constexpr int KHALF  = K / 2;
    constexpr int BLD    = KHALF + 8;      // padded LDS row -> benign aliasing
    constexpr int KC     = KHALF / 8;
    constexpr int CPT    = (128 * KC) / 512;

    int t = threadIdx.x;
    int wave = t >> 6, lane = t & 63;
    int wm = wave >> 1, wn = wave & 1;     // 4x2 wave grid
    int fr = lane & 15, fq = lane >> 4;

    int grow0 = bx * 256;

    const u16* arow[4];                    // tiled mean base (group + fr slot)
    const u16* aroot[4];                   // tiled root base
    #pragma unroll
    for (int r = 0; r < 4; ++r) {
        int row = grow0 + wm * 64 + r * 16 + fr;
        if (row >= nrows) row = nrows - 1;
        arow[r]  = M + (size_t)(row >> 4) * (16 * KM) + (row & 15) * 8;
        aroot[r] = rootT + (size_t)(row >> 4) * 2048 + (row & 15) * 8;
    }

    f32x4 acc[4][4] = {};
    bf16x8 af[2][4];

#define LOADA(buf, gks_) do {                                              \
    int k0_ = (gks_) * 32;                                                 \
    _Pragma("unroll")                                                      \
    for (int r_ = 0; r_ < 4; ++r_) {                                       \
        const u16* p_ = (k0_ < KM) ? (arow[r_] + k0_ * 16)                 \
                                   : (aroot[r_] + (k0_ - KM) * 16);        \
        af[buf][r_] = *(const bf16x8*)(p_ + fq * 128);                     \
    }                                                                      \
} while (0)

#define STAGEB(ph_) do {                                                   \
    _Pragma("unroll")                                                      \
    for (int i_ = 0; i_ < CPT; ++i_) {                                     \
        int c_ = i_ * 512 + t;                                             \
        int col_ = c_ / KC, kc_ = c_ - col_ * KC;                          \
        U4 v_ = *(const U4*)(WT + (size_t)col_ * K + (ph_) * KHALF + kc_ * 8); \
        *(U4*)(Bsm + col_ * BLD + kc_ * 8) = v_;                           \
    }                                                                      \
} while (0)

    LOADA(0, 0);
    STAGEB(0);
    __syncthreads();

    #pragma unroll
    for (int ph = 0; ph < 2; ++ph) {
        if (ph == 1) {
            __syncthreads();
            STAGEB(1);
            __syncthreads();
        }
        #pragma unroll
        for (int ksl = 0; ksl < KSH; ++ksl) {
            int gks = ph * KSH + ksl;
            int cur = gks & 1;
            if (gks + 1 < KSTEPS) LOADA((gks + 1) & 1, gks + 1);
            bf16x8 bfv[4];
            #pragma unroll
            for (int c = 0; c < 4; ++c)
                bfv[c] = *(const bf16x8*)(Bsm + (wn * 64 + c * 16 + fr) * BLD
                                          + ksl * 32 + fq * 8);
            #pragma unroll
            for (int r = 0; r < 4; ++r)
                #pragma unroll
                for (int c = 0; c < 4; ++c)
                    acc[r][c] = __builtin_amdgcn_mfma_f32_16x16x32_bf16(
                        af[cur][r], bfv[c], acc[r][c], 0, 0, 0);
        }
    }
#undef LOADA
#undef STAGEB

    float4 b4 = *(const float4*)(bias + wn * 64 + 4 * fr);
    int colb = wn * 64 + 4 * fr;
    #pragma unroll
    for (int r = 0; r < 4; ++r) {
        #pragma unroll
        for (int g = 0; g < 4; ++g) {
            int orow = grow0 + wm * 64 + r * 16 + fq * 4 + g;
            if (orow < nrows) {
                float v0 = acc[r][0][g] + b4.x;
                float v1 = acc[r][1][g] + b4.y;
                float v2 = acc[r][2][g] + b4.z;
                float v3 = acc[r][3][g] + b4.w;
                if (relu) {
                    v0 = fmaxf(v0, 0.0f); v1 = fmaxf(v1, 0.0f);
                    v2 = fmaxf(v2, 0.0f); v3 = fmaxf(v3, 0.0f);
                }
                size_t ob = (size_t)orow * 128 + colb;
                if (out_f32) {
                    float4 st = { v0, v1, v2, v3 };
                    *(float4*)((float*)out + ob) = st;
                } else {
                    U2 st;
                    st.a = (u32)f2bf(v0) | ((u32)f2bf(v1) << 16);
                    st.b = (u32)f2bf(v2) | ((u32)f2bf(v3) << 16);
                    *(U2*)((u16*)out + ob) = st;
                    if (outT) {   // tiled copy: next layer's root operand
                        size_t toff = (size_t)(orow >> 4) * 2048
                                    + (size_t)(colb >> 3) * 128
                                    + (orow & 15) * 8 + (colb & 7);
                        *(U2*)(outT + toff) = st;
                    }
                }
            }
        }
    }
}

// one launch per layer: paper blocks (K=384) then author blocks (K=256)
__global__ __launch_bounds__(512, 4) void gemm_dual(
    const u16* __restrict__ Mp, const u16* __restrict__ fpT,
    const u16* __restrict__ WTp, const float* __restrict__ bp,
    void* __restrict__ op, u16* __restrict__ opT,
    const u16* __restrict__ Ma, const u16* __restrict__ faT,
    const u16* __restrict__ WTa, const float* __restrict__ ba,
    void* __restrict__ oa, u16* __restrict__ oaT,
    int out_f32, int relu, int nbp)
{
    __shared__ __align__(16) u16 Bsm[128 * 200];   // max BLD = 192+8 -> 51.2KB
    if ((int)blockIdx.x < nbp)
        gemm_body<384, 256>(Bsm, blockIdx.x, Mp, fpT, WTp, bp, op, opT, out_f32, NPAPER, relu);
    else
        gemm_body<256, 128>(Bsm, blockIdx.x - nbp, Ma, faT, WTa, ba, oa, oaT, out_f32, NAUTH, relu);
}

extern "C" void kernel_launch(void* const* d_in, const int* in_sizes, int n_in,
                              void* d_out, int out_size, void* d_ws, size_t ws_size,
                              hipStream_t stream)
{
    const void* xp  = d_in[0];
    const void* xa  = d_in[1];
    const void* Wm1 = d_in[2];
    const void* b1  = d_in[3];
    const void* Wr1 = d_in[4];
    const void* Wm2 = d_in[5];
    const void* b2  = d_in[6];
    const void* Wr2 = d_in[7];
    const int* e0s = (const int*)d_in[8];
    const int* e0d = (const int*)d_in[9];
    const int* e1s = (const int*)d_in[10];
    const int* e1d = (const int*)d_in[11];
    const int* e2s = (const int*)d_in[12];
    const int* e2d = (const int*)d_in[13];
    int E0 = in_sizes[8], E1 = in_sizes[10], E2 = in_sizes[12];

    // ---- ws layout, ~224 MiB total (ws poison fill is ~307 MB) ----
    char* w = (char*)d_ws;
    int*   flags  = (int*)w;                          // 5 ints
    float* biasp1 = (float*)(w + 256);
    float* biasa1 = biasp1 + 128;
    float* biasp2 = biasa1 + 128;
    float* biasa2 = biasp2 + 128;
    u16*   WTp1   = (u16*)(w + 2304);                 // 128x384
    u16*   WTa1   = WTp1 + 49152;                     // 128x256
    u16*   WTp2   = WTa1 + 32768;
    u16*   WTa2   = WTp2 + 49152;
    int*   rp_all = (int*)(WTa2 + 32768);             // 250001 (+pad)
    int*   cnt_all  = rp_all + 250004;                // 250000
    int*   cur_all  = cnt_all + 250000;               // 250000
    int*   srt_all  = cur_all + 250000;               // 600000
    u16*   xpb   = (u16*)(srt_all + 600000);          // 100000x128 bf16 row-major
    u16*   xab   = xpb + (size_t)NPAPER * 128;        // 50000x128
    u16*   hpw   = xab + (size_t)NAUTH * 128;         // 100000x128
    u16*   haw   = hpw + (size_t)NPAPER * 128;        // 50000x128
    u16*   Mp    = haw + (size_t)NAUTH * 128;         // 100000x256 (tiled means)
    u16*   Ma    = Mp + (size_t)NPAPER * 256;         // 50000x128  (tiled means)
    u16*   xpbT  = Ma + (size_t)NAUTH * 128;          // tiled feature copies
    u16*   xabT  = xpbT + (size_t)NPAPER * 128;
    u16*   hpwT  = xabT + (size_t)NAUTH * 128;
    u16*   hawT  = hpwT + (size_t)NPAPER * 128;
    int*   partials = (int*)(hawT + (size_t)NAUTH * 128);  // 256 ints

    float* outp = (float*)d_out;                      // final output f32
    float* outa = outp + (size_t)NPAPER * 128;

    // memset first (independent of flags; hist inside fused_pre needs zeros)
    hipMemsetAsync(cnt_all, 0, (size_t)NROWS_ALL * 4, stream);

    detect_dtypes<<<1, 256, 0, stream>>>(e0s, (const u32*)xp, (const u32*)Wm1,
                                         (const u32*)b1, flags);

    int nb0 = (E0 + 255) / 256, nb1 = (E1 + 255) / 256, nb2 = (E2 + 255) / 256;
    int nbc;
    {
        size_t ntot = (size_t)(NPAPER + NAUTH) * 128;
        nbc = (int)((ntot / 8 + 255) / 256);          // 9375
    }
    // convert (dual-layout) + weight prep + hist in one launch
    fused_pre<<<nbc + 642 + nb0 + nb1 + nb2, 256, 0, stream>>>(
        xp, xa, xpb, xab, xpbT, xabT,
        Wm1, b1, Wr1, Wm2, b2, Wr2,
        WTp1, WTa1, biasp1, biasa1, WTp2, WTa2, biasp2, biasa2,
        e0d, e1d, e2d, E0, E1, E2, nb0, nb1, cnt_all, nbc, flags);

    // ---- CSR scan + scatter ----
    {
        int nbs = (NROWS_ALL + 1023) / 1024;           // 245 <= 256
        scan_blksum<<<nbs, 256, 0, stream>>>(cnt_all, NROWS_ALL, partials);
        scan_partials<<<1, 256, 0, stream>>>(partials, nbs);
        scan_write<<<nbs, 256, 0, stream>>>(cnt_all, NROWS_ALL, partials, rp_all, cur_all);
        scatter3<<<nb0 + nb1 + nb2, 256, 0, stream>>>(e0s, e0d, e1s, e1d, e2s, e2d,
                                                      E0, E1, E2, nb0, nb1,
                                                      cur_all, srt_all, flags);
    }

    const int NBP = (NPAPER + 255) / 256;             // 391 paper blocks
    const int NBA = (NAUTH + 255) / 256;              // 196 author blocks
    const int NAGG = ((NROWS_ALL + 1) / 2 * 64 + 255) / 256;  // 2 rows/wave

    for (int layer = 0; layer < 2; ++layer) {
        const u16* fp  = layer ? hpw  : xpb;          // row-major (agg gathers)
        const u16* fa  = layer ? haw  : xab;
        const u16* fpT = layer ? hpwT : xpbT;         // tiled (gemm root)
        const u16* faT = layer ? hawT : xabT;
        void* op = layer ? (void*)outp : (void*)hpw;
        void* oa = layer ? (void*)outa : (void*)haw;
        u16* opT = layer ? nullptr : hpwT;            // layer0 also emits tiled
        u16* oaT = layer ? nullptr : hawT;
        int of32 = layer ? 1 : 0;
        const u16* WTp = layer ? WTp2 : WTp1;
        const u16* WTa = layer ? WTa2 : WTa1;
        const float* bp = layer ? biasp2 : biasp1;
        const float* ba = layer ? biasa2 : biasa1;
        int relu = layer ? 0 : 1;

        // all 3 aggregations in one launch, 2 rows per wave, tiled-mean output
        agg_all<<<NAGG, 256, 0, stream>>>(fp, fa, rp_all, srt_all, Mp, Ma);

        // both GEMMs in one launch (256 rows / 8 waves per block)
        gemm_dual<<<NBP + NBA, 512, 0, stream>>>(
            Mp, fpT, WTp, bp, op, opT, Ma, faT, WTa, ba, oa, oaT, of32, relu, NBP);
    }
}

// Round 11
// 405.528 us; speedup vs baseline: 1.0996x; 1.0996x over previous
//
#include <hip/hip_runtime.h>

typedef unsigned short u16;
typedef unsigned int u32;
typedef __bf16 bf16x8 __attribute__((ext_vector_type(8)));
typedef float f32x4 __attribute__((ext_vector_type(4)));

#define NPAPER 100000
#define NAUTH  50000
#define NROWS_ALL (2 * NPAPER + NAUTH)

struct alignas(16) U4 { u32 a, b, c, d; };
struct alignas(8)  U2 { u32 a, b; };
struct alignas(16) F4 { float x, y, z, w; };

__device__ __forceinline__ float bf2f(u16 u) {
    union { u32 i; float f; } v; v.i = ((u32)u) << 16; return v.f;
}
__device__ __forceinline__ u16 f2bf(float f) {
    union { float f; u32 i; } v; v.f = f;
    u32 u = v.i;
    return (u16)((u + 0x7FFFu + ((u >> 16) & 1u)) >> 16);
}

// flags: [0]=idx_is_int64 [1]=x_is_f32 [2]=W_is_f32 [3]=b_is_f32
__device__ __forceinline__ float ldf(const void* p, size_t i, int f32) {
    return f32 ? ((const float*)p)[i] : bf2f(((const u16*)p)[i]);
}

__global__ void detect_dtypes(const int* __restrict__ e, const u32* __restrict__ x,
                              const u32* __restrict__ w, const u32* __restrict__ bb,
                              int* __restrict__ flags)
{
    int t = threadIdx.x, wave = t >> 6, lane = t & 63;
    if (wave == 0) {
        int v = e[lane];
        unsigned long long m = __ballot((lane & 1) && v == 0);
        if (lane == 0) flags[0] = (__popcll(m) >= 24) ? 1 : 0;
    } else {
        const u32* p = (wave == 1) ? x : ((wave == 2) ? w : bb);
        u32 wd = p[lane];
        int ex = (int)((wd >> 7) & 0xFFu);   // exponent of low-half-as-bf16
        unsigned long long m = __ballot(ex >= 105 && ex <= 140);
        if (lane == 0) flags[wave] = (__popcll(m) >= 40) ? 0 : 1;   // 1 = f32
    }
}

// ---- epilogue column permutation for GEMM B-rows ----
// B-row j (0..127) holds PHYSICAL output column n(j):
//   s=j>>6, u=j&63, c=u>>4, fr=u&15  ->  n = s*64 + fr*4 + c
__device__ __forceinline__ int permcol(int j) {
    int s = j >> 6, u = j & 63, c = u >> 4, fr = u & 15;
    return s * 64 + fr * 4 + c;
}

// ---- fused prologue: convert_x + prep_weights(both layers) + hist3 ----
__global__ __launch_bounds__(256) void fused_pre(
    const void* __restrict__ xp, const void* __restrict__ xa,
    u16* __restrict__ xpb, u16* __restrict__ xab,
    const void* __restrict__ Wm1, const void* __restrict__ b1, const void* __restrict__ Wr1,
    const void* __restrict__ Wm2, const void* __restrict__ b2, const void* __restrict__ Wr2,
    u16* __restrict__ WTp1, u16* __restrict__ WTa1,
    float* __restrict__ biasp1, float* __restrict__ biasa1,
    u16* __restrict__ WTp2, u16* __restrict__ WTa2,
    float* __restrict__ biasp2, float* __restrict__ biasa2,
    const int* __restrict__ e0d, const int* __restrict__ e1d, const int* __restrict__ e2d,
    int E0, int E1, int E2, int nb0, int nb1,
    int* __restrict__ cnt, int nbc,
    const int* __restrict__ flags)
{
    int b = blockIdx.x;
    int t = threadIdx.x;
    if (b < nbc) {
        // ---- convert_x ----
        int f32 = flags[1];
        size_t i = ((size_t)b * 256 + t) * 8;
        const size_t np = (size_t)NPAPER * 128, ntot = np + (size_t)NAUTH * 128;
        if (i >= ntot) return;
        const void* s; u16* d; size_t off;
        if (i < np) { s = xp; d = xpb; off = i; }
        else        { s = xa; d = xab; off = i - np; }
        alignas(16) u16 o[8];
        if (f32) {
            const F4* f = (const F4*)((const float*)s + off);
            F4 f0 = f[0], f1 = f[1];
            o[0] = f2bf(f0.x); o[1] = f2bf(f0.y); o[2] = f2bf(f0.z); o[3] = f2bf(f0.w);
            o[4] = f2bf(f1.x); o[5] = f2bf(f1.y); o[6] = f2bf(f1.z); o[7] = f2bf(f1.w);
        } else {
            *(U4*)o = *(const U4*)((const u16*)s + off);
        }
        *(U4*)(d + off) = *(const U4*)o;
        return;
    }
    b -= nbc;
    if (b < 642) {
        // ---- prep_weights (both layers) ----
        int half = b >= 321;
        const void* Wm = half ? Wm2 : Wm1;
        const void* bb = half ? b2  : b1;
        const void* Wr = half ? Wr2 : Wr1;
        u16* WTp = half ? WTp2 : WTp1;
        u16* WTa = half ? WTa2 : WTa1;
        float* biasp = half ? biasp2 : biasp1;
        float* biasa = half ? biasa2 : biasa1;

        int wf = flags[2], bf = flags[3];
        int tid = (b - half * 321) * 256 + t;
        if (tid < 49152) {
            int j = tid / 384, k = tid - j * 384;
            int n = permcol(j);
            float v;
            if (k < 128)      v = ldf(Wm, k * 128 + n, wf);
            else if (k < 256) v = ldf(Wm, 16384 + (k - 128) * 128 + n, wf);
            else              v = ldf(Wr, (k - 256) * 128 + n, wf)
                                + ldf(Wr, 16384 + (k - 256) * 128 + n, wf);
            WTp[j * 384 + k] = f2bf(v);
        } else if (tid < 81920) {
            int idx = tid - 49152;
            int j = idx >> 8, k = idx & 255;
            int n = permcol(j);
            float v = (k < 128) ? ldf(Wm, 2 * 16384 + k * 128 + n, wf)
                                : ldf(Wr, 2 * 16384 + (k - 128) * 128 + n, wf);
            WTa[j * 256 + k] = f2bf(v);
        } else if (tid < 82176) {
            int i = tid - 81920;
            if (i < 128) biasp[i] = ldf(bb, i, bf) + ldf(bb, 128 + i, bf);
            else         biasa[i - 128] = ldf(bb, 256 + (i - 128), bf);
        }
        return;
    }
    b -= 642;
    {
        // ---- hist3 ----
        const int* dptr; int E, base, i;
        if (b < nb0)            { dptr = e0d; E = E0; base = 0;          i = b * 256 + t; }
        else if (b < nb0 + nb1) { dptr = e1d; E = E1; base = NPAPER;     i = (b - nb0) * 256 + t; }
        else                    { dptr = e2d; E = E2; base = 2 * NPAPER; i = (b - nb0 - nb1) * 256 + t; }
        if (i >= E) return;
        int d = dptr[flags[0] ? 2 * i : i];
        atomicAdd(&cnt[base + d], 1);
    }
}

__global__ __launch_bounds__(256) void scan_blksum(
    const int* __restrict__ cnt, int N, int* __restrict__ partials)
{
    __shared__ int ws[4];
    int t = threadIdx.x, lane = t & 63, wave = t >> 6;
    int i0 = blockIdx.x * 1024 + t * 4;
    int s = 0;
    #pragma unroll
    for (int j = 0; j < 4; ++j) {
        int i = i0 + j;
        if (i < N) s += cnt[i];
    }
    #pragma unroll
    for (int off = 32; off; off >>= 1) s += __shfl_xor(s, off);
    if (lane == 0) ws[wave] = s;
    __syncthreads();
    if (t == 0) partials[blockIdx.x] = ws[0] + ws[1] + ws[2] + ws[3];
}

__global__ __launch_bounds__(256) void scan_partials(int* __restrict__ partials, int nb)
{
    __shared__ int bs[256];
    int t = threadIdx.x;
    bs[t] = (t < nb) ? partials[t] : 0;
    __syncthreads();
    for (int off = 1; off < 256; off <<= 1) {
        int u = (t >= off) ? bs[t - off] : 0;
        __syncthreads();
        bs[t] += u;
        __syncthreads();
    }
    if (t < nb) partials[t] = (t == 0) ? 0 : bs[t - 1];
}

__global__ __launch_bounds__(256) void scan_write(
    const int* __restrict__ cnt, int N, const int* __restrict__ partials,
    int* __restrict__ rowptr, int* __restrict__ cursor)
{
    __shared__ int ws[4];
    int t = threadIdx.x, lane = t & 63, wave = t >> 6;
    int i0 = blockIdx.x * 1024 + t * 4;
    int v[4];
    #pragma unroll
    for (int j = 0; j < 4; ++j) {
        int i = i0 + j;
        v[j] = (i < N) ? cnt[i] : 0;
    }
    int s = v[0] + v[1] + v[2] + v[3];
    int sc = s;
    #pragma unroll
    for (int off = 1; off < 64; off <<= 1) {
        int u = __shfl_up(sc, off);
        if (lane >= off) sc += u;
    }
    if (lane == 63) ws[wave] = sc;
    __syncthreads();
    int woff = 0;
    #pragma unroll
    for (int wv = 0; wv < 3; ++wv) if (wv < wave) woff += ws[wv];
    int run = partials[blockIdx.x] + woff + (sc - s);
    #pragma unroll
    for (int j = 0; j < 4; ++j) {
        int i = i0 + j;
        if (i < N) {
            rowptr[i] = run; cursor[i] = run;
            run += v[j];
            if (i == N - 1) rowptr[N] = run;
        }
    }
}

__global__ __launch_bounds__(256) void scatter3(
    const int* __restrict__ e0s, const int* __restrict__ e0d,
    const int* __restrict__ e1s, const int* __restrict__ e1d,
    const int* __restrict__ e2s, const int* __restrict__ e2d,
    int E0, int E1, int E2, int nb0, int nb1,
    int* __restrict__ cursor, int* __restrict__ srt,
    const int* __restrict__ flags)
{
    int b = blockIdx.x;
    const int* sptr; const int* dptr; int E, base, i;
    if (b < nb0)            { sptr = e0s; dptr = e0d; E = E0; base = 0;          i = b * 256 + threadIdx.x; }
    else if (b < nb0 + nb1) { sptr = e1s; dptr = e1d; E = E1; base = NPAPER;     i = (b - nb0) * 256 + threadIdx.x; }
    else                    { sptr = e2s; dptr = e2d; E = E2; base = 2 * NPAPER; i = (b - nb0 - nb1) * 256 + threadIdx.x; }
    if (i >= E) return;
    int ii = flags[0] ? 2 * i : i;
    int d = dptr[ii];
    int pos = atomicAdd(&cursor[base + d], 1);
    srt[pos] = sptr[ii];
}

// ---- unified CSR gather-mean: TWO adjacent rows per wave (row-major out) ----
__device__ __forceinline__ void agg_resolve(int r, const u16* xp, const u16* xa,
                                            u16* Mp, u16* Ma,
                                            const u16*& x, u16*& d)
{
    if (r < NPAPER)          { x = xp; d = Mp + (size_t)r * 256; }
    else if (r < 2 * NPAPER) { x = xa; d = Mp + (size_t)(r - NPAPER) * 256 + 128; }
    else                     { x = xp; d = Ma + (size_t)(r - 2 * NPAPER) * 128; }
}

__global__ __launch_bounds__(256) void agg_all(
    const u16* __restrict__ xp, const u16* __restrict__ xa,
    const int* __restrict__ rp_all, const int* __restrict__ srt,
    u16* __restrict__ Mp, u16* __restrict__ Ma)
{
    int wid = (blockIdx.x * 256 + threadIdx.x) >> 6;
    int lane = threadIdx.x & 63;
    int r0 = wid * 2;
    if (r0 >= NROWS_ALL) return;
    int has1 = (r0 + 1 < NROWS_ALL);

    int eA0 = rp_all[r0], eA1 = rp_all[r0 + 1];
    int eB0 = eA1, eB1 = has1 ? rp_all[r0 + 2] : eA1;

    const u16 *xA, *xB; u16 *dA, *dB;
    agg_resolve(r0, xp, xa, Mp, Ma, xA, dA);
    agg_resolve(has1 ? r0 + 1 : r0, xp, xa, Mp, Ma, xB, dB);

    float a0A = 0.0f, a1A = 0.0f, a0B = 0.0f, a1B = 0.0f;
    int itA = (eA1 - eA0 + 3) >> 2;
    int itB = (eB1 - eB0 + 3) >> 2;
    int iters = itA > itB ? itA : itB;

#define GATH4(e_, elast_, x_, q0_, q1_) do {                                \
    int el_ = (elast_) - 1;                                                 \
    int i1_ = (e_) + 1, i2_ = (e_) + 2, i3_ = (e_) + 3;                     \
    int c1_ = i1_ < (elast_) ? i1_ : el_;                                   \
    int c2_ = i2_ < (elast_) ? i2_ : el_;                                   \
    int c3_ = i3_ < (elast_) ? i3_ : el_;                                   \
    int s0_ = srt[e_], s1_ = srt[c1_], s2_ = srt[c2_], s3_ = srt[c3_];      \
    u32 p0_ = ((const u32*)((x_) + (size_t)s0_ * 128))[lane];               \
    u32 p1_ = ((const u32*)((x_) + (size_t)s1_ * 128))[lane];               \
    u32 p2_ = ((const u32*)((x_) + (size_t)s2_ * 128))[lane];               \
    u32 p3_ = ((const u32*)((x_) + (size_t)s3_ * 128))[lane];               \
    p1_ = (i1_ < (elast_)) ? p1_ : 0u;                                      \
    p2_ = (i2_ < (elast_)) ? p2_ : 0u;                                      \
    p3_ = (i3_ < (elast_)) ? p3_ : 0u;                                      \
    q0_ += bf2f((u16)(p0_ & 0xFFFFu)) + bf2f((u16)(p1_ & 0xFFFFu))          \
         + bf2f((u16)(p2_ & 0xFFFFu)) + bf2f((u16)(p3_ & 0xFFFFu));         \
    q1_ += bf2f((u16)(p0_ >> 16)) + bf2f((u16)(p1_ >> 16))                  \
         + bf2f((u16)(p2_ >> 16)) + bf2f((u16)(p3_ >> 16));                 \
} while (0)

    for (int k = 0; k < iters; ++k) {
        if (k < itA) GATH4(eA0 + 4 * k, eA1, xA, a0A, a1A);
        if (k < itB) GATH4(eB0 + 4 * k, eB1, xB, a0B, a1B);
    }
#undef GATH4

    float rcpA = 1.0f / fmaxf((float)(eA1 - eA0), 1.0f);
    ((u32*)dA)[lane] = (u32)f2bf(a0A * rcpA) | ((u32)f2bf(a1A * rcpA) << 16);
    if (has1) {
        float rcpB = 1.0f / fmaxf((float)(eB1 - eB0), 1.0f);
        ((u32*)dB)[lane] = (u32)f2bf(a0B * rcpB) | ((u32)f2bf(a1B * rcpB) << 16);
    }
}

// ---- fused GEMM/bias/relu body: out[nrows][128] = [M | root] @ WT^T + bias ----
// 256 rows per block, 8 waves in an 8x1 grid: each wave owns 32 rows x ALL
// 128 cols -> A rows are fetched exactly once per block (no wn duplication),
// halving A-load instruction count vs the 4x2 grid.  B (WT) staged fully into
// LDS in 2 K-halves (3 barriers/block); A fragments loaded per-lane from
// global, double-buffered -> barrier-free K-loop.  Epilogue uses permuted
// column order: frag c owns phys col (c>>2)*64 + 4*fr + (c&3) -> two vector
// stores per output row.
template<int K, int KM>
__device__ __forceinline__ void gemm_body(
    u16* __restrict__ Bsm, int bx,
    const u16* __restrict__ M, int Mstride, const u16* __restrict__ root,
    const u16* __restrict__ WT, const float* __restrict__ bias,
    void* __restrict__ out, int out_f32, int nrows, int relu)
{
    constexpr int KSTEPS = K / 32;
    constexpr int KSH    = KSTEPS / 2;
    constexpr int KHALF  = K / 2;
    constexpr int BLD    = KHALF + 8;      // padded LDS row -> benign aliasing
    constexpr int KC     = KHALF / 8;
    constexpr int CPT    = (128 * KC) / 512;

    int t = threadIdx.x;
    int wave = t >> 6, lane = t & 63;      // wave = row-group 0..7
    int fr = lane & 15, fq = lane >> 4;

    int grow0 = bx * 256;

    const u16* arow[2];
    const u16* aroot[2];
    #pragma unroll
    for (int r = 0; r < 2; ++r) {
        int row = grow0 + wave * 32 + r * 16 + fr;
        if (row >= nrows) row = nrows - 1;
        arow[r]  = M + (size_t)row * Mstride;
        aroot[r] = root + (size_t)row * 128;
    }

    f32x4 acc[2][8] = {};
    bf16x8 af[2][2];

#define LOADA(buf, gks_) do {                                              \
    int k0_ = (gks_) * 32;                                                 \
    _Pragma("unroll")                                                      \
    for (int r_ = 0; r_ < 2; ++r_) {                                       \
        const u16* p_ = (k0_ < KM) ? (arow[r_] + k0_)                      \
                                   : (aroot[r_] + (k0_ - KM));             \
        af[buf][r_] = *(const bf16x8*)(p_ + fq * 8);                       \
    }                                                                      \
} while (0)

#define STAGEB(ph_) do {                                                   \
    _Pragma("unroll")                                                      \
    for (int i_ = 0; i_ < CPT; ++i_) {                                     \
        int c_ = i_ * 512 + t;                                             \
        int col_ = c_ / KC, kc_ = c_ - col_ * KC;                          \
        U4 v_ = *(const U4*)(WT + (size_t)col_ * K + (ph_) * KHALF + kc_ * 8); \
        *(U4*)(Bsm + col_ * BLD + kc_ * 8) = v_;                           \
    }                                                                      \
} while (0)

    LOADA(0, 0);
    STAGEB(0);
    __syncthreads();

    #pragma unroll
    for (int ph = 0; ph < 2; ++ph) {
        if (ph == 1) {
            __syncthreads();
            STAGEB(1);
            __syncthreads();
        }
        #pragma unroll
        for (int ksl = 0; ksl < KSH; ++ksl) {
            int gks = ph * KSH + ksl;
            int cur = gks & 1;
            if (gks + 1 < KSTEPS) LOADA((gks + 1) & 1, gks + 1);
            bf16x8 bfv[8];
            #pragma unroll
            for (int c = 0; c < 8; ++c)
                bfv[c] = *(const bf16x8*)(Bsm + (c * 16 + fr) * BLD
                                          + ksl * 32 + fq * 8);
            #pragma unroll
            for (int r = 0; r < 2; ++r)
                #pragma unroll
                for (int c = 0; c < 8; ++c)
                    acc[r][c] = __builtin_amdgcn_mfma_f32_16x16x32_bf16(
                        af[cur][r], bfv[c], acc[r][c], 0, 0, 0);
        }
    }
#undef LOADA
#undef STAGEB

    // frag c -> phys col (c>>2)*64 + 4*fr + (c&3)
    float4 b4lo = *(const float4*)(bias + 4 * fr);
    float4 b4hi = *(const float4*)(bias + 64 + 4 * fr);
    #pragma unroll
    for (int r = 0; r < 2; ++r) {
        #pragma unroll
        for (int g = 0; g < 4; ++g) {
            int orow = grow0 + wave * 32 + r * 16 + fq * 4 + g;
            if (orow < nrows) {
                float v0 = acc[r][0][g] + b4lo.x;
                float v1 = acc[r][1][g] + b4lo.y;
                float v2 = acc[r][2][g] + b4lo.z;
                float v3 = acc[r][3][g] + b4lo.w;
                float v4 = acc[r][4][g] + b4hi.x;
                float v5 = acc[r][5][g] + b4hi.y;
                float v6 = acc[r][6][g] + b4hi.z;
                float v7 = acc[r][7][g] + b4hi.w;
                if (relu) {
                    v0 = fmaxf(v0, 0.0f); v1 = fmaxf(v1, 0.0f);
                    v2 = fmaxf(v2, 0.0f); v3 = fmaxf(v3, 0.0f);
                    v4 = fmaxf(v4, 0.0f); v5 = fmaxf(v5, 0.0f);
                    v6 = fmaxf(v6, 0.0f); v7 = fmaxf(v7, 0.0f);
                }
                size_t ob = (size_t)orow * 128 + 4 * fr;
                if (out_f32) {
                    float4 s0 = { v0, v1, v2, v3 };
                    float4 s1 = { v4, v5, v6, v7 };
                    *(float4*)((float*)out + ob) = s0;
                    *(float4*)((float*)out + ob + 64) = s1;
                } else {
                    U2 s0, s1;
                    s0.a = (u32)f2bf(v0) | ((u32)f2bf(v1) << 16);
                    s0.b = (u32)f2bf(v2) | ((u32)f2bf(v3) << 16);
                    s1.a = (u32)f2bf(v4) | ((u32)f2bf(v5) << 16);
                    s1.b = (u32)f2bf(v6) | ((u32)f2bf(v7) << 16);
                    *(U2*)((u16*)out + ob) = s0;
                    *(U2*)((u16*)out + ob + 64) = s1;
                }
            }
        }
    }
}

// one launch per layer: paper blocks (K=384) then author blocks (K=256)
__global__ __launch_bounds__(512, 4) void gemm_dual(
    const u16* __restrict__ Mp, const u16* __restrict__ fp,
    const u16* __restrict__ WTp, const float* __restrict__ bp, void* __restrict__ op,
    const u16* __restrict__ Ma, const u16* __restrict__ fa,
    const u16* __restrict__ WTa, const float* __restrict__ ba, void* __restrict__ oa,
    int out_f32, int relu, int nbp)
{
    __shared__ __align__(16) u16 Bsm[128 * 200];   // max BLD = 192+8 -> 51.2KB
    if ((int)blockIdx.x < nbp)
        gemm_body<384, 256>(Bsm, blockIdx.x, Mp, 256, fp, WTp, bp, op, out_f32, NPAPER, relu);
    else
        gemm_body<256, 128>(Bsm, blockIdx.x - nbp, Ma, 128, fa, WTa, ba, oa, out_f32, NAUTH, relu);
}

extern "C" void kernel_launch(void* const* d_in, const int* in_sizes, int n_in,
                              void* d_out, int out_size, void* d_ws, size_t ws_size,
                              hipStream_t stream)
{
    const void* xp  = d_in[0];
    const void* xa  = d_in[1];
    const void* Wm1 = d_in[2];
    const void* b1  = d_in[3];
    const void* Wr1 = d_in[4];
    const void* Wm2 = d_in[5];
    const void* b2  = d_in[6];
    const void* Wr2 = d_in[7];
    const int* e0s = (const int*)d_in[8];
    const int* e0d = (const int*)d_in[9];
    const int* e1s = (const int*)d_in[10];
    const int* e1d = (const int*)d_in[11];
    const int* e2s = (const int*)d_in[12];
    const int* e2d = (const int*)d_in[13];
    int E0 = in_sizes[8], E1 = in_sizes[10], E2 = in_sizes[12];

    // ---- ws layout, ~147 MiB total ----
    char* w = (char*)d_ws;
    int*   flags  = (int*)w;                          // 5 ints
    float* biasp1 = (float*)(w + 256);
    float* biasa1 = biasp1 + 128;
    float* biasp2 = biasa1 + 128;
    float* biasa2 = biasp2 + 128;
    u16*   WTp1   = (u16*)(w + 2304);                 // 128x384
    u16*   WTa1   = WTp1 + 49152;                     // 128x256
    u16*   WTp2   = WTa1 + 32768;
    u16*   WTa2   = WTp2 + 49152;
    int*   rp_all = (int*)(WTa2 + 32768);             // 250001 (+pad)
    int*   cnt_all  = rp_all + 250004;                // 250000
    int*   cur_all  = cnt_all + 250000;               // 250000
    int*   srt_all  = cur_all + 250000;               // 600000
    u16*   xpb   = (u16*)(srt_all + 600000);          // 100000x128 bf16
    u16*   xab   = xpb + (size_t)NPAPER * 128;        // 50000x128
    u16*   hpw   = xab + (size_t)NAUTH * 128;         // 100000x128
    u16*   haw   = hpw + (size_t)NPAPER * 128;        // 50000x128
    u16*   Mp    = haw + (size_t)NAUTH * 128;         // 100000x256 (cites|writes means)
    u16*   Ma    = Mp + (size_t)NPAPER * 256;         // 50000x128  (wb means)
    int*   partials = (int*)(Ma + (size_t)NAUTH * 128);  // 256 ints

    float* outp = (float*)d_out;                      // final output f32
    float* outa = outp + (size_t)NPAPER * 128;

    // memset first (independent of flags; hist inside fused_pre needs zeros)
    hipMemsetAsync(cnt_all, 0, (size_t)NROWS_ALL * 4, stream);

    detect_dtypes<<<1, 256, 0, stream>>>(e0s, (const u32*)xp, (const u32*)Wm1,
                                         (const u32*)b1, flags);

    int nb0 = (E0 + 255) / 256, nb1 = (E1 + 255) / 256, nb2 = (E2 + 255) / 256;
    int nbc;
    {
        size_t ntot = (size_t)(NPAPER + NAUTH) * 128;
        nbc = (int)((ntot / 8 + 255) / 256);          // 9375
    }
    // convert + weight prep + hist in one launch
    fused_pre<<<nbc + 642 + nb0 + nb1 + nb2, 256, 0, stream>>>(
        xp, xa, xpb, xab,
        Wm1, b1, Wr1, Wm2, b2, Wr2,
        WTp1, WTa1, biasp1, biasa1, WTp2, WTa2, biasp2, biasa2,
        e0d, e1d, e2d, E0, E1, E2, nb0, nb1, cnt_all, nbc, flags);

    // ---- CSR scan + scatter ----
    {
        int nbs = (NROWS_ALL + 1023) / 1024;           // 245 <= 256
        scan_blksum<<<nbs, 256, 0, stream>>>(cnt_all, NROWS_ALL, partials);
        scan_partials<<<1, 256, 0, stream>>>(partials, nbs);
        scan_write<<<nbs, 256, 0, stream>>>(cnt_all, NROWS_ALL, partials, rp_all, cur_all);
        scatter3<<<nb0 + nb1 + nb2, 256, 0, stream>>>(e0s, e0d, e1s, e1d, e2s, e2d,
                                                      E0, E1, E2, nb0, nb1,
                                                      cur_all, srt_all, flags);
    }

    const int NBP = (NPAPER + 255) / 256;             // 391 paper blocks
    const int NBA = (NAUTH + 255) / 256;              // 196 author blocks
    const int NAGG = ((NROWS_ALL + 1) / 2 * 64 + 255) / 256;  // 2 rows/wave

    for (int layer = 0; layer < 2; ++layer) {
        const u16* fp = layer ? hpw : xpb;
        const u16* fa = layer ? haw : xab;
        void* op = layer ? (void*)outp : (void*)hpw;
        void* oa = layer ? (void*)outa : (void*)haw;
        int of32 = layer ? 1 : 0;
        const u16* WTp = layer ? WTp2 : WTp1;
        const u16* WTa = layer ? WTa2 : WTa1;
        const float* bp = layer ? biasp2 : biasp1;
        const float* ba = layer ? biasa2 : biasa1;
        int relu = layer ? 0 : 1;

        // all 3 aggregations in one launch, 2 rows per wave
        agg_all<<<NAGG, 256, 0, stream>>>(fp, fa, rp_all, srt_all, Mp, Ma);

        // both GEMMs in one launch (256 rows / 8 waves, 8x1 grid per block)
        gemm_dual<<<NBP + NBA, 512, 0, stream>>>(
            Mp, fp, WTp, bp, op, Ma, fa, WTa, ba, oa, of32, relu, NBP);
    }
}